// Round 1
// baseline (1164.363 us; speedup 1.0000x reference)
//
#include <hip/hip_runtime.h>
#include <math.h>

#define NN   32768
#define DD   512
#define PP   256
#define LV   8
#define ROWS 32
#define SSTR 261   // score row stride (floats): 261 % 32 = 5, gcd(5,32)=1 -> conflict-free scans

// ---------------------------------------------------------------- cnorm[j] = sum_d cb[j][d]^2
__global__ __launch_bounds__(256) void prep_kernel(const float* __restrict__ cb,
                                                   float* __restrict__ cnorm)
{
    int j = threadIdx.x;
    const float* row = cb + (size_t)j * DD;
    float s = 0.f;
    for (int d = 0; d < DD; d += 4) {
        float4 v = *(const float4*)&row[d];
        s += v.x * v.x; s += v.y * v.y; s += v.z * v.z; s += v.w * v.w;
    }
    cnorm[j] = s;
}

// ---------------------------------------------------------------- T[l][s] = sum_{j: src_l(j)==s} cb[j]
// grid (LV, 8): blockIdx.y splits the D range 8x64 for parallelism; T must be pre-zeroed.
__global__ __launch_bounds__(256) void buildT_kernel(const float* __restrict__ cb,
                                                     const float* __restrict__ noise_u,
                                                     const float* __restrict__ correct_p,
                                                     float* __restrict__ T)
{
    int l = blockIdx.x;
    int dpart = blockIdx.y;
    int j = threadIdx.x;
    float cp = correct_p[0];
    float u = noise_u[l * PP + j];
    int src;
    if (u <= cp) {
        src = j;
    } else {
        float step = (1.0f - cp) / 256.0f;             // mirrors (1.0-cp)/p_cb in fp32
        int integer = (int)floorf((u - cp) / step);
        src = (j + 1 + integer) & 255;                 // values in [0,511] -> % 256
    }
    const float* crow = cb + (size_t)j * DD + dpart * 64;
    float*       trow = T  + ((size_t)l * PP + src) * DD + dpart * 64;
    for (int d = 0; d < 64; d++) atomicAdd(&trow[d], crow[d]);
}

// ---------------------------------------------------------------- main: scores -> prefix argmin -> outs + sse
__global__ __launch_bounds__(256, 4) void main_kernel(
    const float* __restrict__ x, const float* __restrict__ cb,
    const float* __restrict__ T, const float* __restrict__ cnorm,
    float* __restrict__ out, float* __restrict__ sse)
{
    __shared__ float smem[ROWS * SSTR];   // phase A: x-chunk [32][128] aliased at offset 0; phase B: scores [32][261]
    __shared__ int   idx_sm[ROWS][LV];
    __shared__ float red[256];
    __shared__ float cnl[PP];

    const int t    = threadIdx.x;
    const int row0 = blockIdx.x * ROWS;
    const int cg   = t & 63;              // codeword group: cols {cg, cg+64, cg+128, cg+192}
    const int rg   = t >> 6;              // row group: rows rg*8 .. rg*8+7 (one wave per rg -> LDS broadcast)

    cnl[t] = cnorm[t];

    float acc[8][4];
    #pragma unroll
    for (int r = 0; r < 8; r++)
        #pragma unroll
        for (int c = 0; c < 4; c++) acc[r][c] = 0.f;

    // ---- phase A: 32x256 GEMM (dot products), d chunked by 128 through LDS
    for (int dc = 0; dc < DD; dc += 128) {
        __syncthreads();
        #pragma unroll
        for (int k = 0; k < 4; k++) {
            int i = t + k * 256;          // 1024 float4
            int r = i >> 5;
            int f = i & 31;
            *(float4*)&smem[r * 128 + f * 4] =
                *(const float4*)&x[(size_t)(row0 + r) * DD + dc + f * 4];
        }
        __syncthreads();
        #pragma unroll 4
        for (int dd = 0; dd < 128; dd += 4) {
            float4 b0 = *(const float4*)&cb[(size_t)(cg      ) * DD + dc + dd];
            float4 b1 = *(const float4*)&cb[(size_t)(cg +  64) * DD + dc + dd];
            float4 b2 = *(const float4*)&cb[(size_t)(cg + 128) * DD + dc + dd];
            float4 b3 = *(const float4*)&cb[(size_t)(cg + 192) * DD + dc + dd];
            #pragma unroll
            for (int rr = 0; rr < 8; rr++) {
                float4 xa = *(const float4*)&smem[(rg * 8 + rr) * 128 + dd];  // wave-uniform broadcast
                acc[rr][0] += xa.x * b0.x; acc[rr][0] += xa.y * b0.y;
                acc[rr][0] += xa.z * b0.z; acc[rr][0] += xa.w * b0.w;
                acc[rr][1] += xa.x * b1.x; acc[rr][1] += xa.y * b1.y;
                acc[rr][1] += xa.z * b1.z; acc[rr][1] += xa.w * b1.w;
                acc[rr][2] += xa.x * b2.x; acc[rr][2] += xa.y * b2.y;
                acc[rr][2] += xa.z * b2.z; acc[rr][2] += xa.w * b2.w;
                acc[rr][3] += xa.x * b3.x; acc[rr][3] += xa.y * b3.y;
                acc[rr][3] += xa.z * b3.z; acc[rr][3] += xa.w * b3.w;
            }
        }
    }

    // ---- phase B: scores to LDS (store -2*dot; combine as (xn + cnorm[j]) - 2dot like the reference)
    __syncthreads();
    #pragma unroll
    for (int rr = 0; rr < 8; rr++) {
        int r = rg * 8 + rr;
        smem[r * SSTR + cg      ] = -2.f * acc[rr][0];
        smem[r * SSTR + cg +  64] = -2.f * acc[rr][1];
        smem[r * SSTR + cg + 128] = -2.f * acc[rr][2];
        smem[r * SSTR + cg + 192] = -2.f * acc[rr][3];
    }
    __syncthreads();
    if (t < ROWS) {
        int r = t;
        const float* xr = &x[(size_t)(row0 + r) * DD];
        float xn = 0.f;
        for (int d = 0; d < DD; d += 4) {
            float4 v = *(const float4*)&xr[d];
            xn += v.x * v.x; xn += v.y * v.y; xn += v.z * v.z; xn += v.w * v.w;
        }
        const float* sc = &smem[r * SSTR];
        float best = (xn + cnl[0]) + sc[0];
        int bi = 0;
        int lvl = 0, nextb = 2;
        for (int j = 1; j < PP; j++) {
            float v = (xn + cnl[j]) + sc[j];
            if (v < best) { best = v; bi = j; }   // strict < == first-index tie-break (jnp.argmin)
            if (j + 1 == nextb) { idx_sm[r][lvl] = bi; lvl++; nextb <<= 1; }
        }
    }
    __syncthreads();

    // ---- phase C: gather T rows, write outs, accumulate per-level SSE
    float part[LV];
    #pragma unroll 1
    for (int l = 0; l < LV; l++) {
        float lsum = 0.f;
        #pragma unroll 4
        for (int k = 0; k < 16; k++) {
            int i  = t + k * 256;        // 4096 float4 per level per block
            int r  = i >> 7;             // single r per wave -> idx broadcast
            int d4 = (i & 127) * 4;
            int id = idx_sm[r][l];
            float4 q  = *(const float4*)&T[((size_t)l * PP + id) * DD + d4];
            float4 xv = *(const float4*)&x[(size_t)(row0 + r) * DD + d4];
            float dx0 = q.x - xv.x, dx1 = q.y - xv.y, dx2 = q.z - xv.z, dx3 = q.w - xv.w;
            float4 o;
            o.x = xv.x + dx0; o.y = xv.y + dx1; o.z = xv.z + dx2; o.w = xv.w + dx3;  // mirrors x + (q - x)
            *(float4*)&out[((size_t)l * NN + row0 + r) * DD + d4] = o;
            lsum += dx0 * dx0; lsum += dx1 * dx1; lsum += dx2 * dx2; lsum += dx3 * dx3;
        }
        part[l] = lsum;
    }
    #pragma unroll 1
    for (int l = 0; l < LV; l++) {
        __syncthreads();
        red[t] = part[l];
        __syncthreads();
        for (int s = 128; s > 0; s >>= 1) {
            if (t < s) red[t] += red[t + s];
            __syncthreads();
        }
        if (t == 0) atomicAdd(&sse[l], red[0]);
    }
}

// ---------------------------------------------------------------- losses
__global__ __launch_bounds__(256) void finalize_kernel(
    const float* __restrict__ cb, const float* __restrict__ prev,
    const float* __restrict__ sse, float* __restrict__ losses)
{
    __shared__ float rowsse[PP];
    int t = threadIdx.x;
    const float* p = prev + (size_t)t * DD;
    const float* c = cb   + (size_t)t * DD;
    float s = 0.f;
    for (int d = 0; d < DD; d += 4) {
        float4 pv = *(const float4*)&p[d];
        float4 cv = *(const float4*)&c[d];
        float d0 = pv.x - cv.x, d1 = pv.y - cv.y, d2 = pv.z - cv.z, d3 = pv.w - cv.w;
        s += d0 * d0; s += d1 * d1; s += d2 * d2; s += d3 * d3;
    }
    rowsse[t] = s;
    __syncthreads();
    if (t == 0) {
        const float inv_nd = 1.0f / ((float)NN * (float)DD);
        float pacc = 0.f;
        int j = 0;
        for (int l = 0; l < LV; l++) {
            int nact = 2 << l;
            while (j < nact) { pacc += rowsse[j]; j++; }
            float q    = sse[l] * inv_nd;
            float e    = (l <= 1) ? q : 0.f;                                   // LAMBDA_C branch
            float prox = (l >= 1) ? 0.33f * (pacc / ((float)nact * (float)DD)) // LAMBDA_P
                                  : 0.f;
            losses[l] = q + 0.1f * e + prox;
        }
    }
}

// ---------------------------------------------------------------- actives = codebook copy
__global__ __launch_bounds__(256) void copy_actives_kernel(const float* __restrict__ cb,
                                                           float* __restrict__ dst)
{
    int i = blockIdx.x * 256 + threadIdx.x;   // 32768 float4
    *(float4*)&dst[(size_t)i * 4] = *(const float4*)&cb[(size_t)i * 4];
}

// ----------------------------------------------------------------
extern "C" void kernel_launch(void* const* d_in, const int* in_sizes, int n_in,
                              void* d_out, int out_size, void* d_ws, size_t ws_size,
                              hipStream_t stream)
{
    const float* x    = (const float*)d_in[0];  // inputs   (32768,512)
    const float* cb   = (const float*)d_in[1];  // codebook (256,512)
    const float* prev = (const float*)d_in[2];  // prev_vecs(256,512)
    const float* cp   = (const float*)d_in[3];  // correct_p(1,)
    const float* nu   = (const float*)d_in[4];  // noise_u  (8,256)
    // d_in[5] = num_vectors (=256, compile-time constant here)

    float* ws    = (float*)d_ws;
    float* T     = ws;                           // 8*256*512 floats (4 MB)
    float* cnorm = ws + (size_t)LV * PP * DD;    // 256
    float* sseb  = cnorm + PP;                   // 8

    float* out    = (float*)d_out;
    float* losses = out + (size_t)LV * NN * DD;  // 8 scalars
    float* actv   = losses + LV;                 // 256*512

    hipMemsetAsync(d_ws, 0, ((size_t)LV * PP * DD + PP + LV) * sizeof(float), stream);
    prep_kernel<<<1, 256, 0, stream>>>(cb, cnorm);
    buildT_kernel<<<dim3(LV, 8), 256, 0, stream>>>(cb, nu, cp, T);
    main_kernel<<<NN / ROWS, 256, 0, stream>>>(x, cb, T, cnorm, out, sseb);
    finalize_kernel<<<1, 256, 0, stream>>>(cb, prev, sseb, losses);
    copy_actives_kernel<<<(PP * DD) / (4 * 256), 256, 0, stream>>>(cb, actv);
}

// Round 2
// 764.224 us; speedup vs baseline: 1.5236x; 1.5236x over previous
//
#include <hip/hip_runtime.h>
#include <math.h>

#define NN 32768
#define DD 512
#define PP 256
#define LV 8
#define GR 64            // rows per gemm block
#define SSTR 257         // score row stride (odd -> conflict-free)
#define EMIT_BLOCKS 4096

typedef float f4 __attribute__((ext_vector_type(4)));

// ---------------------------------------------------------------- cnorm[j] = sum_d cb[j][d]^2
__global__ __launch_bounds__(256) void prep_cnorm_kernel(const float* __restrict__ cb,
                                                         float* __restrict__ cnorm)
{
    __shared__ float xp[256];
    const int t = threadIdx.x;
    const int r = t & 63, q = t >> 6;
    const float* row = cb + (size_t)(blockIdx.x * 64 + r) * DD + q * 128;
    float s = 0.f;
    #pragma unroll 8
    for (int f = 0; f < 32; f++) {
        f4 v = *(const f4*)&row[f * 4];
        s += v.x * v.x; s += v.y * v.y; s += v.z * v.z; s += v.w * v.w;
    }
    xp[q * 64 + r] = s;
    __syncthreads();
    if (t < 64) cnorm[blockIdx.x * 64 + t] = (xp[t] + xp[64 + t]) + (xp[128 + t] + xp[192 + t]);
}

// ---------------------------------------------------------------- T identity part: T[l][s] = (u<=cp) ? cb[s] : 0
// Writes EVERY element of T -> no memset needed.
__global__ __launch_bounds__(256) void buildT_A_kernel(const float* __restrict__ cb,
                                                       const float* __restrict__ nu,
                                                       const float* __restrict__ cp_p,
                                                       float* __restrict__ T)
{
    const int l = blockIdx.x, p = blockIdx.y;
    const int t = threadIdx.x;
    const float cp = cp_p[0];
    #pragma unroll 1
    for (int it = 0; it < 8; it++) {
        int s = p * 16 + it * 2 + (t >> 7);       // wave-uniform row
        float u = nu[l * PP + s];
        int d4 = (t & 127) * 4;
        f4 v = {0.f, 0.f, 0.f, 0.f};
        if (u <= cp) v = *(const f4*)&cb[(size_t)s * DD + d4];
        *(f4*)&T[((size_t)l * PP + s) * DD + d4] = v;
    }
}

// ---------------------------------------------------------------- T remap part: ~10% rows scatter-add
__global__ __launch_bounds__(256) void buildT_B_kernel(const float* __restrict__ cb,
                                                       const float* __restrict__ nu,
                                                       const float* __restrict__ cp_p,
                                                       float* __restrict__ T)
{
    const int l = blockIdx.x;
    const int t = threadIdx.x;
    const float cp = cp_p[0];
    __shared__ int lj[PP], ls[PP];
    __shared__ int cnt;
    if (t == 0) cnt = 0;
    __syncthreads();
    float u = nu[l * PP + t];
    if (u > cp) {
        float step = (1.0f - cp) / 256.0f;                 // mirrors (1.0-cp)/p_cb fp32
        int integer = (int)floorf((u - cp) / step);
        int src = (t + 1 + integer) & 255;
        int pos = atomicAdd(&cnt, 1);
        lj[pos] = t; ls[pos] = src;
    }
    __syncthreads();
    int n = cnt;
    for (int i = 0; i < n; i++) {
        int jj = lj[i], ss = ls[i];
        float*       dst = &T[((size_t)l * PP + ss) * DD];
        const float* sr  = &cb[(size_t)jj * DD];
        atomicAdd(&dst[t * 2],     sr[t * 2]);
        atomicAdd(&dst[t * 2 + 1], sr[t * 2 + 1]);
    }
}

// ---------------------------------------------------------------- scores + prefix argmin -> idx[N][8]
__global__ __launch_bounds__(256, 4) void gemm_argmin_kernel(const float* __restrict__ x,
                                                             const float* __restrict__ cb,
                                                             const float* __restrict__ cnorm,
                                                             int* __restrict__ idx)
{
    __shared__ float sm[GR * SSTR];   // phase A: xtile [64][128] floats; phase B: scores [64][257]
    __shared__ float xn_sm[GR];
    __shared__ float xp[256];
    __shared__ float cnl[PP];

    const int t    = threadIdx.x;
    const int row0 = blockIdx.x * GR;
    const int cg   = t & 63;          // cols {cg, cg+64, cg+128, cg+192}
    const int rg   = t >> 6;          // rows rg*16 .. rg*16+15

    cnl[t] = cnorm[t];

    float acc[16][4];
    #pragma unroll
    for (int r = 0; r < 16; r++)
        #pragma unroll
        for (int c = 0; c < 4; c++) acc[r][c] = 0.f;

    for (int dc = 0; dc < DD; dc += 128) {
        __syncthreads();
        #pragma unroll
        for (int k = 0; k < 8; k++) {           // stage x[64][128]: 2048 float4
            int i = t + k * 256;
            int r = i >> 5, f = i & 31;
            *(f4*)&sm[r * 128 + f * 4] = *(const f4*)&x[(size_t)(row0 + r) * DD + dc + f * 4];
        }
        __syncthreads();
        #pragma unroll 2
        for (int dd = 0; dd < 128; dd += 4) {
            f4 b0 = *(const f4*)&cb[(size_t)(cg      ) * DD + dc + dd];
            f4 b1 = *(const f4*)&cb[(size_t)(cg +  64) * DD + dc + dd];
            f4 b2 = *(const f4*)&cb[(size_t)(cg + 128) * DD + dc + dd];
            f4 b3 = *(const f4*)&cb[(size_t)(cg + 192) * DD + dc + dd];
            #pragma unroll
            for (int rr = 0; rr < 16; rr++) {
                f4 xa = *(const f4*)&sm[(rg * 16 + rr) * 128 + dd];   // wave-uniform broadcast
                acc[rr][0] += xa.x * b0.x; acc[rr][0] += xa.y * b0.y;
                acc[rr][0] += xa.z * b0.z; acc[rr][0] += xa.w * b0.w;
                acc[rr][1] += xa.x * b1.x; acc[rr][1] += xa.y * b1.y;
                acc[rr][1] += xa.z * b1.z; acc[rr][1] += xa.w * b1.w;
                acc[rr][2] += xa.x * b2.x; acc[rr][2] += xa.y * b2.y;
                acc[rr][2] += xa.z * b2.z; acc[rr][2] += xa.w * b2.w;
                acc[rr][3] += xa.x * b3.x; acc[rr][3] += xa.y * b3.y;
                acc[rr][3] += xa.z * b3.z; acc[rr][3] += xa.w * b3.w;
            }
        }
    }
    __syncthreads();   // all threads done reading xtile before scores overwrite it

    #pragma unroll
    for (int rr = 0; rr < 16; rr++) {
        int r = rg * 16 + rr;
        sm[r * SSTR + cg      ] = -2.f * acc[rr][0];
        sm[r * SSTR + cg +  64] = -2.f * acc[rr][1];
        sm[r * SSTR + cg + 128] = -2.f * acc[rr][2];
        sm[r * SSTR + cg + 192] = -2.f * acc[rr][3];
    }

    // xn[r] via 4-way split (L2-hot x rows)
    {
        int r = t & 63, q = t >> 6;
        const float* xr = &x[(size_t)(row0 + r) * DD + q * 128];
        float s = 0.f;
        #pragma unroll 8
        for (int f = 0; f < 32; f++) {
            f4 v = *(const f4*)&xr[f * 4];
            s += v.x * v.x; s += v.y * v.y; s += v.z * v.z; s += v.w * v.w;
        }
        xp[q * 64 + r] = s;
    }
    __syncthreads();
    if (t < 64) xn_sm[t] = (xp[t] + xp[64 + t]) + (xp[128 + t] + xp[192 + t]);
    __syncthreads();

    // prefix argmin: thread = (row r, level-pair lp); wave-uniform trip counts
    {
        int r = t & 63, lp = t >> 6;
        int n    = 4 << (2 * lp);     // 4,16,64,256
        int half = n >> 1;
        float xn = xn_sm[r];
        const float* sc = &sm[r * SSTR];
        float best = (xn + cnl[0]) + sc[0];
        int bi = 0;
        int* od = &idx[(size_t)(row0 + r) * LV + 2 * lp];
        for (int j = 1; j < n; j++) {
            float v = (xn + cnl[j]) + sc[j];
            if (v < best) { best = v; bi = j; }    // strict < = first-index tie-break
            if (j + 1 == half) od[0] = bi;
        }
        od[1] = bi;
    }
}

// ---------------------------------------------------------------- streaming emit: outs + sse partials
__global__ __launch_bounds__(256) void emit_kernel(const float* __restrict__ x,
                                                   const float* __restrict__ T,
                                                   const int* __restrict__ idx,
                                                   float* __restrict__ out,
                                                   float* __restrict__ partial)
{
    __shared__ int   idx_sm[64];
    __shared__ float red[4 * LV];
    const int t    = threadIdx.x;
    const int row0 = blockIdx.x * 8;
    if (t < 64) idx_sm[t] = idx[(size_t)row0 * LV + t];
    __syncthreads();

    float sse[LV];
    #pragma unroll
    for (int l = 0; l < LV; l++) sse[l] = 0.f;

    #pragma unroll 1
    for (int it = 0; it < 4; it++) {
        int rl = it * 2 + (t >> 7);               // wave-uniform local row
        int r  = row0 + rl;
        int d4 = (t & 127) * 4;
        f4 xv = __builtin_nontemporal_load((const f4*)&x[(size_t)r * DD + d4]);
        #pragma unroll
        for (int l = 0; l < LV; l++) {
            int id = idx_sm[rl * LV + l];
            f4 q = *(const f4*)&T[((size_t)l * PP + id) * DD + d4];
            float dx0 = q.x - xv.x, dx1 = q.y - xv.y, dx2 = q.z - xv.z, dx3 = q.w - xv.w;
            f4 o;
            o.x = xv.x + dx0; o.y = xv.y + dx1; o.z = xv.z + dx2; o.w = xv.w + dx3;  // x + (q - x)
            __builtin_nontemporal_store(o, (f4*)&out[((size_t)l * NN + r) * DD + d4]);
            sse[l] += dx0 * dx0; sse[l] += dx1 * dx1; sse[l] += dx2 * dx2; sse[l] += dx3 * dx3;
        }
    }
    #pragma unroll
    for (int l = 0; l < LV; l++) {
        float v = sse[l];
        #pragma unroll
        for (int off = 32; off; off >>= 1) v += __shfl_down(v, off);
        if ((t & 63) == 0) red[(t >> 6) * LV + l] = v;
    }
    __syncthreads();
    if (t < LV)
        partial[(size_t)t * EMIT_BLOCKS + blockIdx.x] =
            (red[t] + red[LV + t]) + (red[2 * LV + t] + red[3 * LV + t]);
}

// ---------------------------------------------------------------- actives copy + per-row prox SSE
__global__ __launch_bounds__(256) void actives_kernel(const float* __restrict__ cb,
                                                      const float* __restrict__ prev,
                                                      float* __restrict__ actv,
                                                      float* __restrict__ rowsse)
{
    const int t = threadIdx.x;
    size_t i = (size_t)blockIdx.x * 2048 + (size_t)t * 8;
    int row = (int)(i >> 9);                       // wave-uniform (64 thr x 8 floats = 512)
    f4 c0 = *(const f4*)&cb[i];
    f4 c1 = *(const f4*)&cb[i + 4];
    *(f4*)&actv[i]     = c0;
    *(f4*)&actv[i + 4] = c1;
    f4 p0 = *(const f4*)&prev[i];
    f4 p1 = *(const f4*)&prev[i + 4];
    float s = 0.f;
    s += (p0.x - c0.x) * (p0.x - c0.x); s += (p0.y - c0.y) * (p0.y - c0.y);
    s += (p0.z - c0.z) * (p0.z - c0.z); s += (p0.w - c0.w) * (p0.w - c0.w);
    s += (p1.x - c1.x) * (p1.x - c1.x); s += (p1.y - c1.y) * (p1.y - c1.y);
    s += (p1.z - c1.z) * (p1.z - c1.z); s += (p1.w - c1.w) * (p1.w - c1.w);
    #pragma unroll
    for (int off = 32; off; off >>= 1) s += __shfl_down(s, off);
    if ((t & 63) == 0) rowsse[row] = s;
}

// ---------------------------------------------------------------- losses
__global__ __launch_bounds__(256) void finalize_kernel(const float* __restrict__ partial,
                                                       const float* __restrict__ rowsse,
                                                       float* __restrict__ losses)
{
    __shared__ float ssev[LV];
    __shared__ float rs[PP];
    const int t = threadIdx.x;
    const int l = t >> 5, i = t & 31;
    float s = 0.f;
    for (int k = 0; k < EMIT_BLOCKS / 32; k++)
        s += partial[(size_t)l * EMIT_BLOCKS + i + k * 32];
    #pragma unroll
    for (int off = 16; off; off >>= 1) s += __shfl_down(s, off, 32);
    if (i == 0) ssev[l] = s;
    rs[t] = rowsse[t];
    __syncthreads();
    if (t == 0) {
        const float inv_nd = 1.0f / ((float)NN * (float)DD);
        float pacc = 0.f;
        int j = 0;
        for (int l2 = 0; l2 < LV; l2++) {
            float q = ssev[l2] * inv_nd;
            float e = (l2 <= 1) ? q : 0.f;                  // LAMBDA_C levels
            float prox = 0.f;
            if (l2 >= 1) {
                int np_ = 1 << l2;                          // 2^l rows (FIXED: was 2^(l+1))
                while (j < np_) { pacc += rs[j]; j++; }
                prox = 0.33f * (pacc / ((float)np_ * (float)DD));
            }
            losses[l2] = q + 0.1f * e + prox;
        }
    }
}

// ----------------------------------------------------------------
extern "C" void kernel_launch(void* const* d_in, const int* in_sizes, int n_in,
                              void* d_out, int out_size, void* d_ws, size_t ws_size,
                              hipStream_t stream)
{
    const float* x    = (const float*)d_in[0];  // (32768,512)
    const float* cb   = (const float*)d_in[1];  // (256,512)
    const float* prev = (const float*)d_in[2];  // (256,512)
    const float* cp   = (const float*)d_in[3];  // (1,)
    const float* nu   = (const float*)d_in[4];  // (8,256)

    float* T       = (float*)d_ws;                      // 1,048,576 floats (4 MB)
    float* cnorm   = T + (size_t)LV * PP * DD;          // 256
    float* partial = cnorm + PP;                        // 8*4096 = 32768
    float* rowsse  = partial + LV * EMIT_BLOCKS;        // 256
    int*   idx     = (int*)(rowsse + PP);               // 32768*8 ints (1 MB)

    float* out    = (float*)d_out;                      // (8,32768,512)
    float* losses = out + (size_t)LV * NN * DD;         // (8,)
    float* actv   = losses + LV;                        // (256,512)

    prep_cnorm_kernel<<<4, 256, 0, stream>>>(cb, cnorm);
    buildT_A_kernel<<<dim3(LV, 16), 256, 0, stream>>>(cb, nu, cp, T);
    buildT_B_kernel<<<LV, 256, 0, stream>>>(cb, nu, cp, T);
    gemm_argmin_kernel<<<NN / GR, 256, 0, stream>>>(x, cb, cnorm, idx);
    emit_kernel<<<EMIT_BLOCKS, 256, 0, stream>>>(x, T, idx, out, partial);
    actives_kernel<<<64, 256, 0, stream>>>(cb, prev, actv, rowsse);
    finalize_kernel<<<1, 256, 0, stream>>>(partial, rowsse, losses);
}